// Round 20
// baseline (28.515 us; speedup 1.0000x reference)
//
#include <hip/hip_runtime.h>
#include <hip/hip_bf16.h>
#include <hip/hip_fp16.h>

// Siren fused, 32x32x16 fp16 MFMA, zero-LDS, triple sigma-cancellation.
// R20: OCCUPANCY x1.5 via small body. Issue model (VALU 2cyc, trans 4cyc,
// fits R11/R12/R17 deltas) prices the loop at ~7.8us; measured 27 -> ~19us of
// stall. Single-stream tile (32 pts) halves live regs to ~83 -> honestly fits
// __launch_bounds__(256,6) (85 regs, 6 waves/EU, +50% overlap). One acc chain
// alive at a time; dot = 2 MFMAs with W2 in C-row 0; h=0 half-wave store.
// Grid 1536 blocks = 6144 waves = exact residency at 6/EU.

typedef _Float16 half8 __attribute__((ext_vector_type(8)));
typedef __fp16 fp16x2 __attribute__((ext_vector_type(2)));
typedef float f32x16 __attribute__((ext_vector_type(16)));

#define THREADS 256
#define BLOCKS 1536
#define INV2PI 0.15915494309189535f

__device__ __forceinline__ unsigned packh(float lo, float hi) {
    union { fp16x2 h; unsigned u; } v;
    v.h = __builtin_amdgcn_cvt_pkrtz(lo, hi);
    return v.u;
}

// enc chain: 12 sin + 12 cos of pi*2^j*xd via 2 seeds + 10 double-angle steps.
__device__ __forceinline__ void enc_chain(float xd, float sv[12], float cv[12]) {
    sv[0] = __builtin_amdgcn_sinf(xd * 0.5f);
    cv[0] = __builtin_amdgcn_cosf(xd * 0.5f);
#pragma unroll
    for (int j = 1; j < 6; ++j) {
        float t = sv[j - 1] + sv[j - 1];
        sv[j] = t * cv[j - 1];
        cv[j] = fmaf(-t, sv[j - 1], 1.0f);
    }
    sv[6] = __builtin_amdgcn_sinf(xd * 32.0f);
    cv[6] = __builtin_amdgcn_cosf(xd * 32.0f);
#pragma unroll
    for (int j = 7; j < 12; ++j) {
        float t = sv[j - 1] + sv[j - 1];
        sv[j] = t * cv[j - 1];
        cv[j] = fmaf(-t, sv[j - 1], 1.0f);
    }
}

__global__ __launch_bounds__(THREADS, 6) void siren_mfma_kernel(
    const float* __restrict__ xf,     // [N][2] flat
    const float* __restrict__ W0,     // [48][32]
    const float* __restrict__ W1,     // [32][32]
    const float* __restrict__ W2,     // [32]
    float* __restrict__ out,
    int n, int chunk)                 // chunk = points per wave (multiple of 32)
{
    const int lane = threadIdx.x & 63;
    const int wid = threadIdx.x >> 6;
    const int q = lane & 31, h = lane >> 5;
    const int wgid = blockIdx.x * 4 + wid;

    int p0 = wgid * chunk;
    if (p0 >= n) return;
    const int pend = min(p0 + chunk, n);

    const int c = q;   // weight column for this lane

    // ---- build fragments in-register, once per wave ----
    union F { unsigned u[4]; half8 v; };
    half8 a0[3], a1[2], dd[2];
#pragma unroll
    for (int t = 0; t < 3; ++t) {               // A0: elem e = W0[h*24+8t+e][c]/2pi
        F f;
#pragma unroll
        for (int i = 0; i < 4; ++i)
            f.u[i] = packh(W0[(h * 24 + 8 * t + 2 * i) * 32 + c] * INV2PI,
                           W0[(h * 24 + 8 * t + 2 * i + 1) * 32 + c] * INV2PI);
        a0[t] = f.v;
    }
#pragma unroll
    for (int t = 0; t < 2; ++t) {               // A1: elem e = W1[kap(h,t,e)][c]/2pi
        F f;
#pragma unroll
        for (int i = 0; i < 4; ++i) {
            int e0 = 2 * i, e1 = 2 * i + 1;
            int k0 = (e0 & 3) + 8 * (e0 >> 2) + 4 * h + 16 * t;
            int k1 = (e1 & 3) + 8 * (e1 >> 2) + 4 * h + 16 * t;
            f.u[i] = packh(W1[k0 * 32 + c] * INV2PI, W1[k1 * 32 + c] * INV2PI);
        }
        a1[t] = f.v;
    }
#pragma unroll
    for (int t = 0; t < 2; ++t) {               // dot: W2 in A-row 0 (c==0)
        F f;
#pragma unroll
        for (int i = 0; i < 4; ++i) {
            int e0 = 2 * i, e1 = 2 * i + 1;
            int k0 = (e0 & 3) + 8 * (e0 >> 2) + 4 * h + 16 * t;
            int k1 = (e1 & 3) + 8 * (e1 >> 2) + 4 * h + 16 * t;
            f.u[i] = packh((c == 0) ? W2[k0] : 0.0f, (c == 0) ? W2[k1] : 0.0f);
        }
        dd[t] = f.v;
    }

    f32x16 zacc;
#pragma unroll
    for (int i = 0; i < 16; ++i) zacc[i] = 0.0f;

    // first tile's x in flight (dim h of point p0+q)
    float xa = xf[(p0 + q) * 2 + h];

    for (int p = p0; p < pend; p += 32) {
        // prefetch next tile's x (hides under this tile's compute)
        const int pn = (p + 32 < pend) ? (p + 32) : p;
        float na = xf[(pn + q) * 2 + h];

        // ===== enc + L0 (3 MFMA) =====
        F bf0, bf1, bf2;
        {
            float sv[12], cv[12];
            enc_chain(xa, sv, cv);
            bf0.u[0] = packh(sv[0], sv[1]);  bf0.u[1] = packh(sv[2], sv[3]);
            bf0.u[2] = packh(sv[4], sv[5]);  bf0.u[3] = packh(sv[6], sv[7]);
            bf1.u[0] = packh(sv[8], sv[9]);  bf1.u[1] = packh(sv[10], sv[11]);
            bf1.u[2] = packh(cv[0], cv[1]);  bf1.u[3] = packh(cv[2], cv[3]);
            bf2.u[0] = packh(cv[4], cv[5]);  bf2.u[1] = packh(cv[6], cv[7]);
            bf2.u[2] = packh(cv[8], cv[9]);  bf2.u[3] = packh(cv[10], cv[11]);
        }
        f32x16 acc;
        acc = __builtin_amdgcn_mfma_f32_32x32x16_f16(a0[0], bf0.v, zacc, 0, 0, 0);
        acc = __builtin_amdgcn_mfma_f32_32x32x16_f16(a0[1], bf1.v, acc, 0, 0, 0);
        acc = __builtin_amdgcn_mfma_f32_32x32x16_f16(a0[2], bf2.v, acc, 0, 0, 0);

        // ===== act (v_sin) -> B1 frag in-lane + L1 (2 MFMA) =====
        F b1a, b1b;
#pragma unroll
        for (int i = 0; i < 4; ++i)
            b1a.u[i] = packh(__builtin_amdgcn_sinf(acc[2 * i]),
                             __builtin_amdgcn_sinf(acc[2 * i + 1]));
#pragma unroll
        for (int i = 0; i < 4; ++i)
            b1b.u[i] = packh(__builtin_amdgcn_sinf(acc[8 + 2 * i]),
                             __builtin_amdgcn_sinf(acc[8 + 2 * i + 1]));
        f32x16 acc1;
        acc1 = __builtin_amdgcn_mfma_f32_32x32x16_f16(a1[0], b1a.v, zacc, 0, 0, 0);
        acc1 = __builtin_amdgcn_mfma_f32_32x32x16_f16(a1[1], b1b.v, acc1, 0, 0, 0);

        // ===== act + dot-MFMA (W2 in C-row 0; K-sum = full 32-chan dot) =====
        F b2a, b2b;
#pragma unroll
        for (int i = 0; i < 4; ++i)
            b2a.u[i] = packh(__builtin_amdgcn_sinf(acc1[2 * i]),
                             __builtin_amdgcn_sinf(acc1[2 * i + 1]));
#pragma unroll
        for (int i = 0; i < 4; ++i)
            b2b.u[i] = packh(__builtin_amdgcn_sinf(acc1[8 + 2 * i]),
                             __builtin_amdgcn_sinf(acc1[8 + 2 * i + 1]));
        f32x16 accD;
        accD = __builtin_amdgcn_mfma_f32_32x32x16_f16(dd[0], b2a.v, zacc, 0, 0, 0);
        accD = __builtin_amdgcn_mfma_f32_32x32x16_f16(dd[1], b2b.v, accD, 0, 0, 0);

        // C[0][q] = reg 0 of h=0 lanes: half-wave coalesced 128B store
        if (h == 0) out[p + q] = accD[0];

        xa = na;
    }
}

extern "C" void kernel_launch(void* const* d_in, const int* in_sizes, int n_in,
                              void* d_out, int out_size, void* d_ws, size_t ws_size,
                              hipStream_t stream) {
    const float* xf = (const float*)d_in[0];
    const float* W0 = (const float*)d_in[1];
    const float* W1 = (const float*)d_in[2];
    const float* W2 = (const float*)d_in[3];
    float* out = (float*)d_out;

    const int n = in_sizes[0] / 2;
    const int nwaves = BLOCKS * 4;                       // 6144 waves resident
    const int tiles = (n + 31) / 32;
    const int chunk = ((tiles + nwaves - 1) / nwaves) * 32;  // points per wave
    siren_mfma_kernel<<<BLOCKS, THREADS, 0, stream>>>(xf, W0, W1, W2, out, n, chunk);
}

// Round 21
// 26.871 us; speedup vs baseline: 1.0612x; 1.0612x over previous
//
#include <hip/hip_runtime.h>
#include <hip/hip_bf16.h>
#include <hip/hip_fp16.h>

// Siren fused, 32x32x16 fp16 MFMA, zero-LDS, triple sigma-cancellation.
// R21 = R19 revert (best measured: 26.9us). R20's single-stream/(256,6)
// occupancy trade regressed — consistent with the final model: the kernel is
// transcendental-pipe-throughput-bound (N*68 sins = ~2180 wave-insts/SIMD at
// ~28-30 cyc each ~= 27us). Act sins are algorithmically irreducible; the
// VALU-poly alternative loses (tested R11/R17). Structure: persistent waves
// (1024 blocks, 8 tiles/wave), single launch, in-register fragment build,
// 2-stream 64-pt tile, all activations on v_sin, dot via 2 sigma-cancelled
// MFMAs with the K-sum doing the cross-half reduce, coalesced store.

typedef _Float16 half8 __attribute__((ext_vector_type(8)));
typedef __fp16 fp16x2 __attribute__((ext_vector_type(2)));
typedef float f32x16 __attribute__((ext_vector_type(16)));

#define THREADS 256
#define BLOCKS 1024
#define INV2PI 0.15915494309189535f

__device__ __forceinline__ unsigned packh(float lo, float hi) {
    union { fp16x2 h; unsigned u; } v;
    v.h = __builtin_amdgcn_cvt_pkrtz(lo, hi);
    return v.u;
}

// enc chain: 12 sin + 12 cos of pi*2^j*xd via 2 seeds + 10 double-angle steps.
__device__ __forceinline__ void enc_chain(float xd, float sv[12], float cv[12]) {
    sv[0] = __builtin_amdgcn_sinf(xd * 0.5f);
    cv[0] = __builtin_amdgcn_cosf(xd * 0.5f);
#pragma unroll
    for (int j = 1; j < 6; ++j) {
        float t = sv[j - 1] + sv[j - 1];
        sv[j] = t * cv[j - 1];
        cv[j] = fmaf(-t, sv[j - 1], 1.0f);
    }
    sv[6] = __builtin_amdgcn_sinf(xd * 32.0f);
    cv[6] = __builtin_amdgcn_cosf(xd * 32.0f);
#pragma unroll
    for (int j = 7; j < 12; ++j) {
        float t = sv[j - 1] + sv[j - 1];
        sv[j] = t * cv[j - 1];
        cv[j] = fmaf(-t, sv[j - 1], 1.0f);
    }
}

__global__ __launch_bounds__(THREADS, 4) void siren_mfma_kernel(
    const float* __restrict__ xf,     // [N][2] flat
    const float* __restrict__ W0,     // [48][32]
    const float* __restrict__ W1,     // [32][32]
    const float* __restrict__ W2,     // [32]
    float* __restrict__ out,
    int n, int chunk)                 // chunk = points per wave (multiple of 64)
{
    const int lane = threadIdx.x & 63;
    const int wid = threadIdx.x >> 6;
    const int q = lane & 31, h = lane >> 5;
    const int wgid = blockIdx.x * 4 + wid;

    int p0 = wgid * chunk;
    if (p0 >= n) return;
    const int pend = min(p0 + chunk, n);

    const int c = q;   // weight column for this lane

    // ---- build fragments in-register, once per wave ----
    union F { unsigned u[4]; half8 v; };
    half8 a0[3], a1[2], d0[2], d1[2];
#pragma unroll
    for (int t = 0; t < 3; ++t) {
        F f;
#pragma unroll
        for (int i = 0; i < 4; ++i) {
            float lo = W0[(h * 24 + 8 * t + 2 * i) * 32 + c] * INV2PI;
            float hi = W0[(h * 24 + 8 * t + 2 * i + 1) * 32 + c] * INV2PI;
            f.u[i] = packh(lo, hi);
        }
        a0[t] = f.v;
    }
#pragma unroll
    for (int t = 0; t < 2; ++t) {
        F f;
#pragma unroll
        for (int i = 0; i < 4; ++i) {
            int e0 = 2 * i, e1 = 2 * i + 1;
            int k0 = (e0 & 3) + 8 * (e0 >> 2) + 4 * h + 16 * t;
            int k1 = (e1 & 3) + 8 * (e1 >> 2) + 4 * h + 16 * t;
            f.u[i] = packh(W1[k0 * 32 + c] * INV2PI, W1[k1 * 32 + c] * INV2PI);
        }
        a1[t] = f.v;
    }
#pragma unroll
    for (int s = 0; s < 2; ++s)
#pragma unroll
        for (int t = 0; t < 2; ++t) {
            F f;
#pragma unroll
            for (int i = 0; i < 4; ++i) {
                int e0 = 2 * i, e1 = 2 * i + 1;
                int k0 = (e0 & 3) + 8 * (e0 >> 2) + 4 * h + 16 * t;
                int k1 = (e1 & 3) + 8 * (e1 >> 2) + 4 * h + 16 * t;
                float lo = (c == 4 * s) ? W2[k0] : 0.0f;
                float hi = (c == 4 * s) ? W2[k1] : 0.0f;
                f.u[i] = packh(lo, hi);
            }
            if (s == 0) d0[t] = f.v; else d1[t] = f.v;
        }

    f32x16 zacc;
#pragma unroll
    for (int i = 0; i < 16; ++i) zacc[i] = 0.0f;

    // ---- first tile's x in flight ----
    float xa = xf[(p0 + q) * 2 + h];
    float xb = xf[(p0 + 32 + q) * 2 + h];

    for (int p = p0; p < pend; p += 64) {
        // prefetch next tile's x (hides under this tile's compute)
        const int pn = (p + 64 < pend) ? (p + 64) : p;
        float na = xf[(pn + q) * 2 + h];
        float nb = xf[(pn + 32 + q) * 2 + h];

        // ===== stream 0: enc + L0 =====
        F bf00, bf01, bf02;
        {
            float sv[12], cv[12];
            enc_chain(xa, sv, cv);
            bf00.u[0] = packh(sv[0], sv[1]);  bf00.u[1] = packh(sv[2], sv[3]);
            bf00.u[2] = packh(sv[4], sv[5]);  bf00.u[3] = packh(sv[6], sv[7]);
            bf01.u[0] = packh(sv[8], sv[9]);  bf01.u[1] = packh(sv[10], sv[11]);
            bf01.u[2] = packh(cv[0], cv[1]);  bf01.u[3] = packh(cv[2], cv[3]);
            bf02.u[0] = packh(cv[4], cv[5]);  bf02.u[1] = packh(cv[6], cv[7]);
            bf02.u[2] = packh(cv[8], cv[9]);  bf02.u[3] = packh(cv[10], cv[11]);
        }
        f32x16 accA;
        accA = __builtin_amdgcn_mfma_f32_32x32x16_f16(a0[0], bf00.v, zacc, 0, 0, 0);
        accA = __builtin_amdgcn_mfma_f32_32x32x16_f16(a0[1], bf01.v, accA, 0, 0, 0);
        accA = __builtin_amdgcn_mfma_f32_32x32x16_f16(a0[2], bf02.v, accA, 0, 0, 0);

        // ===== stream 1: enc + L0 =====
        F bf10, bf11, bf12;
        {
            float sv[12], cv[12];
            enc_chain(xb, sv, cv);
            bf10.u[0] = packh(sv[0], sv[1]);  bf10.u[1] = packh(sv[2], sv[3]);
            bf10.u[2] = packh(sv[4], sv[5]);  bf10.u[3] = packh(sv[6], sv[7]);
            bf11.u[0] = packh(sv[8], sv[9]);  bf11.u[1] = packh(sv[10], sv[11]);
            bf11.u[2] = packh(cv[0], cv[1]);  bf11.u[3] = packh(cv[2], cv[3]);
            bf12.u[0] = packh(cv[4], cv[5]);  bf12.u[1] = packh(cv[6], cv[7]);
            bf12.u[2] = packh(cv[8], cv[9]);  bf12.u[3] = packh(cv[10], cv[11]);
        }
        f32x16 accB;
        accB = __builtin_amdgcn_mfma_f32_32x32x16_f16(a0[0], bf10.v, zacc, 0, 0, 0);
        accB = __builtin_amdgcn_mfma_f32_32x32x16_f16(a0[1], bf11.v, accB, 0, 0, 0);
        accB = __builtin_amdgcn_mfma_f32_32x32x16_f16(a0[2], bf12.v, accB, 0, 0, 0);

        // ===== act0 + L1(0) =====
        F b1a0, b1b0;
#pragma unroll
        for (int i = 0; i < 4; ++i)
            b1a0.u[i] = packh(__builtin_amdgcn_sinf(accA[2 * i]),
                              __builtin_amdgcn_sinf(accA[2 * i + 1]));
#pragma unroll
        for (int i = 0; i < 4; ++i)
            b1b0.u[i] = packh(__builtin_amdgcn_sinf(accA[8 + 2 * i]),
                              __builtin_amdgcn_sinf(accA[8 + 2 * i + 1]));
        f32x16 acc1A;
        acc1A = __builtin_amdgcn_mfma_f32_32x32x16_f16(a1[0], b1a0.v, zacc, 0, 0, 0);
        acc1A = __builtin_amdgcn_mfma_f32_32x32x16_f16(a1[1], b1b0.v, acc1A, 0, 0, 0);

        // ===== act1 + L1(1) =====
        F b1a1, b1b1;
#pragma unroll
        for (int i = 0; i < 4; ++i)
            b1a1.u[i] = packh(__builtin_amdgcn_sinf(accB[2 * i]),
                              __builtin_amdgcn_sinf(accB[2 * i + 1]));
#pragma unroll
        for (int i = 0; i < 4; ++i)
            b1b1.u[i] = packh(__builtin_amdgcn_sinf(accB[8 + 2 * i]),
                              __builtin_amdgcn_sinf(accB[8 + 2 * i + 1]));
        f32x16 acc1B;
        acc1B = __builtin_amdgcn_mfma_f32_32x32x16_f16(a1[0], b1a1.v, zacc, 0, 0, 0);
        acc1B = __builtin_amdgcn_mfma_f32_32x32x16_f16(a1[1], b1b1.v, acc1B, 0, 0, 0);

        // ===== act2 + merged dot-MFMA (d0 -> C row 0, d1 -> C row 4) =====
        F b2a0, b2b0, b2a1, b2b1;
#pragma unroll
        for (int i = 0; i < 4; ++i)
            b2a0.u[i] = packh(__builtin_amdgcn_sinf(acc1A[2 * i]),
                              __builtin_amdgcn_sinf(acc1A[2 * i + 1]));
#pragma unroll
        for (int i = 0; i < 4; ++i)
            b2b0.u[i] = packh(__builtin_amdgcn_sinf(acc1A[8 + 2 * i]),
                              __builtin_amdgcn_sinf(acc1A[8 + 2 * i + 1]));
#pragma unroll
        for (int i = 0; i < 4; ++i)
            b2a1.u[i] = packh(__builtin_amdgcn_sinf(acc1B[2 * i]),
                              __builtin_amdgcn_sinf(acc1B[2 * i + 1]));
#pragma unroll
        for (int i = 0; i < 4; ++i)
            b2b1.u[i] = packh(__builtin_amdgcn_sinf(acc1B[8 + 2 * i]),
                              __builtin_amdgcn_sinf(acc1B[8 + 2 * i + 1]));
        f32x16 accD;
        accD = __builtin_amdgcn_mfma_f32_32x32x16_f16(d0[0], b2a0.v, zacc, 0, 0, 0);
        accD = __builtin_amdgcn_mfma_f32_32x32x16_f16(d0[1], b2b0.v, accD, 0, 0, 0);
        accD = __builtin_amdgcn_mfma_f32_32x32x16_f16(d1[0], b2a1.v, accD, 0, 0, 0);
        accD = __builtin_amdgcn_mfma_f32_32x32x16_f16(d1[1], b2b1.v, accD, 0, 0, 0);

        // reg 0 of lane (h,q) = C[4h][q] = dot of point (h ? 32+q : q)
        out[p + 32 * h + q] = accD[0];

        xa = na;
        xb = nb;
    }
}

extern "C" void kernel_launch(void* const* d_in, const int* in_sizes, int n_in,
                              void* d_out, int out_size, void* d_ws, size_t ws_size,
                              hipStream_t stream) {
    const float* xf = (const float*)d_in[0];
    const float* W0 = (const float*)d_in[1];
    const float* W1 = (const float*)d_in[2];
    const float* W2 = (const float*)d_in[3];
    float* out = (float*)d_out;

    const int n = in_sizes[0] / 2;
    const int nwaves = BLOCKS * 4;
    const int tiles = (n + 63) / 64;
    const int chunk = ((tiles + nwaves - 1) / nwaves) * 64;   // points per wave
    siren_mfma_kernel<<<BLOCKS, THREADS, 0, stream>>>(xf, W0, W1, W2, out, n, chunk);
}